// Round 1
// baseline (590.308 us; speedup 1.0000x reference)
//
#include <hip/hip_runtime.h>
#include <hip/hip_bf16.h>
#include <stdint.h>

#define N_TOK 32768
#define DDIM  768
#define FDIM  3072
#define NCOLS (2*FDIM)      // 6144 rows of W1cat
#define BK    64
#define KTILES (DDIM/BK)    // 12
#define NTILES (NCOLS/256)  // 24 column tiles of 256
#define VD_CHUNK 96

typedef __attribute__((ext_vector_type(8))) short bf16x8;
typedef __attribute__((ext_vector_type(4))) float f32x4;

__device__ __forceinline__ unsigned short f2bf(float f) {
  unsigned u = __builtin_bit_cast(unsigned, f);
  unsigned r = (u + 0x7fffu + ((u >> 16) & 1u)) >> 16;
  return (unsigned short)r;
}

__device__ __forceinline__ void gl_lds16(const void* g, void* l) {
  __builtin_amdgcn_global_load_lds(
      (const __attribute__((address_space(1))) unsigned int*)g,
      (__attribute__((address_space(3))) unsigned int*)l, 16, 0, 0);
}

// ---------- W1[:2] fp32 -> bf16 ----------
__global__ __launch_bounds__(256) void cvt_kernel(const float* __restrict__ src,
                                                  unsigned short* __restrict__ dst) {
  size_t i = ((size_t)blockIdx.x * 256 + threadIdx.x) * 4;
  float4 f = *(const float4*)(src + i);
  ushort4 u;
  u.x = f2bf(f.x); u.y = f2bf(f.y); u.z = f2bf(f.z); u.w = f2bf(f.w);
  *(ushort4*)(dst + i) = u;
}

// ---------- vpart[db][k*F+f] = sum_{d in chunk db} W2[k,d,f] * W3[k,0,d] ----------
__global__ __launch_bounds__(256) void vcalc_kernel(const float* __restrict__ W2,
                                                    const float* __restrict__ W3,
                                                    float* __restrict__ vpart) {
  __shared__ float w3s[VD_CHUNK];
  int k  = blockIdx.x / 12;
  int fb = blockIdx.x % 12;
  int db = blockIdx.y;
  if (threadIdx.x < VD_CHUNK) w3s[threadIdx.x] = W3[k*DDIM + db*VD_CHUNK + threadIdx.x];
  __syncthreads();
  int f = fb*256 + threadIdx.x;
  const float* W2k = W2 + (size_t)k*DDIM*FDIM + (size_t)db*VD_CHUNK*FDIM + f;
  float s = 0.f;
  #pragma unroll 8
  for (int d = 0; d < VD_CHUNK; ++d) s += W2k[(size_t)d*FDIM] * w3s[d];
  vpart[(size_t)db*NCOLS + k*FDIM + f] = s;
}

// ---------- v = sum of 8 vpart chunks; block 0 also computes cbuf[k] ----------
__global__ __launch_bounds__(256) void vfinal_kernel(const float* __restrict__ vpart,
                                                     float* __restrict__ v,
                                                     const float* __restrict__ b2,
                                                     const float* __restrict__ W3,
                                                     const float* __restrict__ b3,
                                                     float* __restrict__ cbuf) {
  int f = blockIdx.x*256 + threadIdx.x;
  float s = 0.f;
  #pragma unroll
  for (int db = 0; db < 8; ++db) s += vpart[(size_t)db*NCOLS + f];
  v[f] = s;
  if (blockIdx.x == 0 && threadIdx.x < 128) {
    int k = threadIdx.x >> 6, lane = threadIdx.x & 63;
    float c = 0.f;
    #pragma unroll
    for (int it = 0; it < DDIM/64; ++it) {
      int i = it*64 + lane;
      c += b2[k*DDIM + i] * W3[k*DDIM + i];
    }
    #pragma unroll
    for (int m = 1; m < 64; m <<= 1) c += __shfl_xor(c, m, 64);
    if (lane == 0) cbuf[k] = c + b3[k];
  }
}

// ---------- gate + x->bf16 + W3 dots ----------
__global__ __launch_bounds__(256) void gate_cvt_kernel(
    const float* __restrict__ x, const float* __restrict__ Wg,
    const float* __restrict__ W3, const float* __restrict__ cbuf,
    unsigned short* __restrict__ xbf,
    float* __restrict__ wgt, float* __restrict__ base) {
  int wid  = threadIdx.x >> 6;
  int lane = threadIdx.x & 63;
  int n = blockIdx.x * 4 + wid;
  const float4* xr = (const float4*)(x + (size_t)n * DDIM);
  ushort4* xw = (ushort4*)(xbf + (size_t)n * DDIM);
  float acc[8] = {0,0,0,0,0,0,0,0};
  float d30 = 0.f, d31 = 0.f;
  #pragma unroll
  for (int it = 0; it < DDIM/256; ++it) {
    int i = it*64 + lane;
    float4 xv = xr[i];
    ushort4 u;
    u.x = f2bf(xv.x); u.y = f2bf(xv.y); u.z = f2bf(xv.z); u.w = f2bf(xv.w);
    xw[i] = u;
    #pragma unroll
    for (int e = 0; e < 8; ++e) {
      float4 w = ((const float4*)(Wg + e*DDIM))[i];
      acc[e] += xv.x*w.x + xv.y*w.y + xv.z*w.z + xv.w*w.w;
    }
    float4 wa = ((const float4*)W3)[i];
    d30 += xv.x*wa.x + xv.y*wa.y + xv.z*wa.z + xv.w*wa.w;
    float4 wb = ((const float4*)(W3 + DDIM))[i];
    d31 += xv.x*wb.x + xv.y*wb.y + xv.z*wb.z + xv.w*wb.w;
  }
  #pragma unroll
  for (int m = 1; m < 64; m <<= 1) {
    #pragma unroll
    for (int e = 0; e < 8; ++e) acc[e] += __shfl_xor(acc[e], m, 64);
    d30 += __shfl_xor(d30, m, 64);
    d31 += __shfl_xor(d31, m, 64);
  }
  if (lane == 0) {
    float l1 = acc[0]; int a1 = 0;
    #pragma unroll
    for (int e = 1; e < 8; ++e) if (acc[e] > l1) { l1 = acc[e]; a1 = e; }
    float l2 = -3.4e38f;
    #pragma unroll
    for (int e = 0; e < 8; ++e) if (e != a1 && acc[e] > l2) l2 = acc[e];
    float w0 = 1.f / (1.f + __expf(l2 - l1));
    float w1 = 1.f - w0;
    wgt[2*n]   = w0;
    wgt[2*n+1] = w1;
    base[n] = w0 * (d30 + cbuf[0]) + w1 * (d31 + cbuf[1]);
  }
}

// ---------- fused GEMM, 256x256 tile, BK=64, 8-phase counted-vmcnt schedule ----------
// part[bn][row] = sum_{col in tile bn(256)} relu(X@W1cat^T + b1)[row][col] * v[col]
// LDS per buffer (64KB): Ak0 @0, Bk0 @16K, Ak1 @32K, Bk1 @48K (each 256 rows x 32 k, 16KB)
// Region issue schedule (tile t): ph0->Ak1(t+1), ph1->Bk1(t+1), ph2->Ak0(t+2), ph3->Bk0(t+2)
// Waits: vmcnt(8) before ph1 and ph3 closing barriers (4 regions = 64KB stay in flight).
__global__ __launch_bounds__(512, 2) void gemm_kernel(
    const unsigned short* __restrict__ A,   // 32768 x 768 bf16
    const unsigned short* __restrict__ B,   // 6144 x 768 bf16 (B^T layout)
    const float* __restrict__ b1,
    const float* __restrict__ v,
    float* __restrict__ part) {             // 24 x 32768
  __shared__ __align__(16) char smem[131072];   // 2 x 64KB

  const int tid  = threadIdx.x;
  const int lane = tid & 63, wid = tid >> 6;
  const int wm = wid >> 2, wn = wid & 3;        // 2M x 4N waves, per-wave C = 128x64
  const int q  = lane >> 4, cl = lane & 15;
  const int bn = blockIdx.x;     // 0..23
  const int bm = blockIdx.y;     // 0..127

  const unsigned short* Ab = A + (size_t)bm * 256 * DDIM;
  const unsigned short* Bb = B + (size_t)bn * 256 * DDIM;

  // staging: region = 256 rows x 32 k; 2 issues x (512 thr x 16B); row stride 64B = 4 slots
  // XOR swizzle (involution): LDS[r][s] holds G[r][s ^ (r&3)]
  const int sg   = (lane & 3) ^ ((lane >> 2) & 3);
  const int soff = (wid*16 + (lane >> 2)) * DDIM + sg * 8;   // elements

  // ds_read byte offsets within region: r*64 + (q ^ (cl&3))*16  (r&3 == cl&3)
  const int swz  = (q ^ (cl & 3)) * 16;
  const int aob  = (wm*128 + cl) * 64 + swz;     // + mhalf*4096 + m*1024 (+ks*32768)
  const int bob  = 16384 + (wn*64 + cl) * 64 + swz; // + n*1024 (+ks*32768)

  f32x4 zero = {0.f, 0.f, 0.f, 0.f};
  f32x4 acc[8][4];
  #pragma unroll
  for (int i = 0; i < 8; ++i)
    #pragma unroll
    for (int j = 0; j < 4; ++j) acc[i][j] = zero;

  auto stageA = [&](int t, int ks) {
    char* dst = smem + (t & 1) * 65536 + ks * 32768;
    const unsigned short* s0 = Ab + soff + t*BK + ks*32;
    gl_lds16(s0,            dst + wid*1024);
    gl_lds16(s0 + 128*DDIM, dst + 8192 + wid*1024);
  };
  auto stageB = [&](int t, int ks) {
    char* dst = smem + (t & 1) * 65536 + ks * 32768 + 16384;
    const unsigned short* s0 = Bb + soff + t*BK + ks*32;
    gl_lds16(s0,            dst + wid*1024);
    gl_lds16(s0 + 128*DDIM, dst + 8192 + wid*1024);
  };

  // prologue: Ak0(0), Bk0(0), Ak1(0), Bk1(0), Ak0(1), Bk0(1); wait first 2 regions
  stageA(0, 0); stageB(0, 0);
  stageA(0, 1); stageB(0, 1);
  stageA(1, 0); stageB(1, 0);
  asm volatile("s_waitcnt vmcnt(8)" ::: "memory");
  __builtin_amdgcn_s_barrier();
  __builtin_amdgcn_sched_barrier(0);

  int buf = 0;
  #pragma unroll
  for (int kt = 0; kt < KTILES; ++kt) {
    const char* ct = smem + buf * 65536;
    bf16x8 af[4], bfr[4];

    // ---- phase 0: ks=0, M-half 0 ----
    #pragma unroll
    for (int n = 0; n < 4; ++n) bfr[n] = *(const bf16x8*)(ct + bob + n*1024);
    #pragma unroll
    for (int m = 0; m < 4; ++m) af[m] = *(const bf16x8*)(ct + aob + m*1024);
    if (kt <= 10) stageA(kt + 1, 1);
    __builtin_amdgcn_s_barrier();
    asm volatile("s_waitcnt lgkmcnt(0)" ::: "memory");
    __builtin_amdgcn_s_setprio(1);
    #pragma unroll
    for (int m = 0; m < 4; ++m)
      #pragma unroll
      for (int n = 0; n < 4; ++n)
        acc[m][n] = __builtin_amdgcn_mfma_f32_16x16x32_bf16(af[m], bfr[n], acc[m][n], 0, 0, 0);
    __builtin_amdgcn_s_setprio(0);
    __builtin_amdgcn_s_barrier();

    // ---- phase 1: ks=0, M-half 1 ----
    #pragma unroll
    for (int m = 0; m < 4; ++m) af[m] = *(const bf16x8*)(ct + aob + 4096 + m*1024);
    if (kt <= 10) stageB(kt + 1, 1);
    __builtin_amdgcn_s_barrier();
    asm volatile("s_waitcnt lgkmcnt(0)" ::: "memory");
    __builtin_amdgcn_s_setprio(1);
    #pragma unroll
    for (int m = 0; m < 4; ++m)
      #pragma unroll
      for (int n = 0; n < 4; ++n)
        acc[4 + m][n] = __builtin_amdgcn_mfma_f32_16x16x32_bf16(af[m], bfr[n], acc[4 + m][n], 0, 0, 0);
    __builtin_amdgcn_s_setprio(0);
    if (kt <= 10) { asm volatile("s_waitcnt vmcnt(8)" ::: "memory"); }
    else          { asm volatile("s_waitcnt vmcnt(0)" ::: "memory"); }
    __builtin_amdgcn_s_barrier();
    __builtin_amdgcn_sched_barrier(0);

    // ---- phase 2: ks=1, M-half 0 ----
    #pragma unroll
    for (int n = 0; n < 4; ++n) bfr[n] = *(const bf16x8*)(ct + 32768 + bob + n*1024);
    #pragma unroll
    for (int m = 0; m < 4; ++m) af[m] = *(const bf16x8*)(ct + 32768 + aob + m*1024);
    if (kt <= 9) stageA(kt + 2, 0);
    __builtin_amdgcn_s_barrier();
    asm volatile("s_waitcnt lgkmcnt(0)" ::: "memory");
    __builtin_amdgcn_s_setprio(1);
    #pragma unroll
    for (int m = 0; m < 4; ++m)
      #pragma unroll
      for (int n = 0; n < 4; ++n)
        acc[m][n] = __builtin_amdgcn_mfma_f32_16x16x32_bf16(af[m], bfr[n], acc[m][n], 0, 0, 0);
    __builtin_amdgcn_s_setprio(0);
    __builtin_amdgcn_s_barrier();

    // ---- phase 3: ks=1, M-half 1 ----
    #pragma unroll
    for (int m = 0; m < 4; ++m) af[m] = *(const bf16x8*)(ct + 32768 + aob + 4096 + m*1024);
    if (kt <= 9) stageB(kt + 2, 0);
    __builtin_amdgcn_s_barrier();
    asm volatile("s_waitcnt lgkmcnt(0)" ::: "memory");
    __builtin_amdgcn_s_setprio(1);
    #pragma unroll
    for (int m = 0; m < 4; ++m)
      #pragma unroll
      for (int n = 0; n < 4; ++n)
        acc[4 + m][n] = __builtin_amdgcn_mfma_f32_16x16x32_bf16(af[m], bfr[n], acc[4 + m][n], 0, 0, 0);
    __builtin_amdgcn_s_setprio(0);
    if (kt <= 9)        { asm volatile("s_waitcnt vmcnt(8)" ::: "memory"); }
    else if (kt == 10)  { asm volatile("s_waitcnt vmcnt(4)" ::: "memory"); }
    else                { asm volatile("s_waitcnt vmcnt(0)" ::: "memory"); }
    __builtin_amdgcn_s_barrier();
    __builtin_amdgcn_sched_barrier(0);

    buf ^= 1;
  }

  // epilogue: relu(acc + b1[col]) * v[col], reduce 256 cols per row
  float vv[4], bb[4];
  #pragma unroll
  for (int n = 0; n < 4; ++n) {
    int cg = bn*256 + wn*64 + n*16 + cl;
    vv[n] = v[cg];
    bb[n] = b1[cg];
  }
  float* red = (float*)smem;   // 256 rows x 4 wn = 4KB (overwrites buf0.Ak0; all reads done)
  #pragma unroll
  for (int mt = 0; mt < 8; ++mt) {
    #pragma unroll
    for (int rr = 0; rr < 4; ++rr) {
      float s = 0.f;
      #pragma unroll
      for (int n = 0; n < 4; ++n) {
        float val = acc[mt][n][rr] + bb[n];
        s += fmaxf(val, 0.f) * vv[n];
      }
      #pragma unroll
      for (int msk = 1; msk < 16; msk <<= 1) s += __shfl_xor(s, msk, 64);
      if (cl == 0) red[(wm*128 + mt*16 + q*4 + rr)*4 + wn] = s;
    }
  }
  __syncthreads();
  if (tid < 256) {
    float r4 = red[tid*4] + red[tid*4+1] + red[tid*4+2] + red[tid*4+3];
    part[(size_t)bn * N_TOK + (size_t)bm*256 + tid] = r4;
  }
}

// ---------- final combine ----------
__global__ __launch_bounds__(256) void final_kernel(const float* __restrict__ part,
                                                    const float* __restrict__ wgt,
                                                    const float* __restrict__ base,
                                                    float* __restrict__ out) {
  int n = blockIdx.x * 256 + threadIdx.x;
  float s0 = 0.f, s1 = 0.f;
  #pragma unroll
  for (int t = 0; t < 12; ++t) s0 += part[(size_t)t*N_TOK + n];
  #pragma unroll
  for (int t = 12; t < 24; ++t) s1 += part[(size_t)t*N_TOK + n];
  out[n] = base[n] + wgt[2*n]*s0 + wgt[2*n+1]*s1;
}

extern "C" void kernel_launch(void* const* d_in, const int* in_sizes, int n_in,
                              void* d_out, int out_size, void* d_ws, size_t ws_size,
                              hipStream_t stream) {
  const float* x  = (const float*)d_in[0];
  const float* Wg = (const float*)d_in[1];
  const float* W1 = (const float*)d_in[2];
  const float* b1 = (const float*)d_in[3];
  const float* W2 = (const float*)d_in[4];
  const float* b2 = (const float*)d_in[5];
  const float* W3 = (const float*)d_in[6];
  const float* b3 = (const float*)d_in[7];
  float* out = (float*)d_out;

  char* ws = (char*)d_ws;
  size_t off = 0;
  auto alloc = [&](size_t bytes) -> char* {
    char* p = ws + off;
    off += (bytes + 255) & ~(size_t)255;
    return p;
  };
  unsigned short* xbf  = (unsigned short*)alloc((size_t)N_TOK * DDIM * 2);   // 48 MB
  unsigned short* w1bf = (unsigned short*)alloc((size_t)NCOLS * DDIM * 2);   // 9 MB
  float* vpart = (float*)alloc((size_t)8 * NCOLS * 4);
  float* v     = (float*)alloc((size_t)NCOLS * 4);
  float* cbuf  = (float*)alloc(64);
  float* wgt   = (float*)alloc((size_t)N_TOK * 2 * 4);
  float* base  = (float*)alloc((size_t)N_TOK * 4);
  float* part  = (float*)alloc((size_t)NTILES * N_TOK * 4);                  // 3.1 MB
  if (off > ws_size) return;

  cvt_kernel<<<(NCOLS*DDIM)/1024, 256, 0, stream>>>(W1, w1bf);
  vcalc_kernel<<<dim3(24, 8), 256, 0, stream>>>(W2, W3, vpart);
  vfinal_kernel<<<NCOLS/256, 256, 0, stream>>>(vpart, v, b2, W3, b3, cbuf);
  gate_cvt_kernel<<<N_TOK/4, 256, 0, stream>>>(x, Wg, W3, cbuf, xbf, wgt, base);
  gemm_kernel<<<dim3(NTILES, N_TOK/256), 512, 0, stream>>>(xbf, w1bf, b1, v, part);
  final_kernel<<<N_TOK/256, 256, 0, stream>>>(part, wgt, base, out);
}